// Round 13
// baseline (206.396 us; speedup 1.0000x reference)
//
#include <hip/hip_runtime.h>
#include <hip/hip_bf16.h>
#include <math.h>

// ---------------------------------------------------------------------------
// SupConLoss on MI355X.
// out = 0.5*CE(predicts,targets) + 0.5*nt_xent(Anorm, temp=0.1)
//       + 0.25*nt_xent2(Anorm, temp=0.05)
// Round 13: fp8 packed register-direct gemm + explicit depth-4 register
// pipeline in the K-loop (load kb+3 while MFMA kb; 4 rotating operand
// buffers = 64 extra VGPRs — free because occupancy is grid-bound at
// ~8 waves/CU). Round 12 showed the compiler alone keeps only ~1 iter of
// load lead (VGPR stayed 88); the rotate forces a ~3-iter (~300cyc) lead
// matching L2 latency. k_final rebuilt without atomics (round-era single
// block did 8192 same-address LDS atomics): stage Srow+lab in LDS, 10
// per-class blockReduce passes.
// Exp sums unshifted (|exponent|<=20, fp32-safe); reference row-max shift
// applied exactly in merge: S_j = s2_raw * exp(-20*vmax_j).
// ---------------------------------------------------------------------------

typedef __attribute__((ext_vector_type(4))) float f32x4;
typedef long long ll;

__device__ __forceinline__ float blockReduceSum(float v, float* sbuf) {
#pragma unroll
  for (int o = 32; o > 0; o >>= 1) v += __shfl_down(v, o, 64);
  int lane = threadIdx.x & 63;
  int w = threadIdx.x >> 6;
  __syncthreads();
  if (lane == 0) sbuf[w] = v;
  __syncthreads();
  return sbuf[0] + sbuf[1] + sbuf[2] + sbuf[3];
}

// --- 1. fused normalize + fp8 fragment-pack + per-row CE -------------------
// Packed layout: 8B chunk index = ((strip*KB + kb)*4 + mt)*64 + lane
//   holds row = strip*64 + mt*16 + (lane&15),
//   k = kb*32 + (lane>>4)*8 .. +7   (one fp8 MFMA A/B fragment slice).
__global__ void k_prep(const float* __restrict__ X, const float* __restrict__ P,
                       const int* __restrict__ tgt, uint2* __restrict__ Pk,
                       float* __restrict__ ce_row, int D, int C) {
  __shared__ float sbuf[8];
  int row = blockIdx.x;
  const float* x = X + (size_t)row * D;
  float ss = 0.f;
  for (int j = threadIdx.x; j < D; j += blockDim.x) {
    float v = x[j];
    ss += v * v;
  }
  ss = blockReduceSum(ss, sbuf);
  float inv = 1.0f / fmaxf(sqrtf(ss), 1e-12f);

  const int KB = D / 32;           // 24
  const int strip = row >> 6;
  const int mt = (row >> 4) & 3;
  const int l4 = row & 15;
  const int nchunk = D / 8;        // 96
  for (int c = threadIdx.x; c < nchunk; c += blockDim.x) {
    int kb = c >> 2;
    int lsub = c & 3;
    int k0 = kb * 32 + lsub * 8;
    float v[8];
#pragma unroll
    for (int j = 0; j < 8; ++j) v[j] = x[k0 + j] * inv;
    unsigned int r0 = 0, r1 = 0;
    r0 = __builtin_amdgcn_cvt_pk_fp8_f32(v[0], v[1], r0, 0);
    r0 = __builtin_amdgcn_cvt_pk_fp8_f32(v[2], v[3], r0, 1);
    r1 = __builtin_amdgcn_cvt_pk_fp8_f32(v[4], v[5], r1, 0);
    r1 = __builtin_amdgcn_cvt_pk_fp8_f32(v[6], v[7], r1, 1);
    int lane = l4 + 16 * lsub;
    size_t chunk = ((size_t)(strip * KB + kb) * 4 + mt) * 64 + lane;
    Pk[chunk] = make_uint2(r0, r1);
  }
  if (threadIdx.x == 0) {
    const float* p = P + (size_t)row * C;
    float m = -INFINITY;
    for (int c = 0; c < C; ++c) m = fmaxf(m, p[c]);
    float s = 0.f;
    for (int c = 0; c < C; ++c) s += expf(p[c] - m);
    int t = tgt[row];
    ce_row[row] = -(p[t] - m - logf(s));
  }
}

// --- 2. single-wave 64x64 fused symmetric GEMM + stats, fp8, reg-pipeline --
// part layout: float4 part[N][NB]; (psum, s1_raw, s2_raw, m2=20*vmax_neg).
__global__ __launch_bounds__(64) void k_gemm_fused(
    const unsigned char* __restrict__ Pk, const int* __restrict__ lab,
    float4* __restrict__ part, int N, int K, int NB) {
  // triangular decode: bid -> (by, bx), by >= bx
  int bid = blockIdx.x;
  int by = (int)((sqrtf(8.f * (float)bid + 1.f) - 1.f) * 0.5f);
  while ((by + 1) * (by + 2) / 2 <= bid) ++by;
  while (by * (by + 1) / 2 > bid) --by;
  int bx = bid - by * (by + 1) / 2;

  const int t = threadIdx.x;  // == lane (single wave)
  const int rowBase = by * 64;
  const int colBase = bx * 64;
  const int KB = K / 32;

  const int myLR = lab[rowBase + t];
  const int myLC = lab[colBase + t];

  // byte offsets: chunk = ((strip*KB+kb)*4+mt)*64 + lane, 8 bytes each
  const unsigned char* aP = Pk + ((size_t)by * KB * 4 * 64 + t) * 8;
  const unsigned char* bP = Pk + ((size_t)bx * KB * 4 * 64 + t) * 8;

  // explicit depth-4 register pipeline
  ll afb[4][4], bfb[4][4];
#pragma unroll
  for (int d = 0; d < 3; ++d) {
    const unsigned char* ak = aP + (size_t)d * 2048;
    const unsigned char* bk = bP + (size_t)d * 2048;
#pragma unroll
    for (int m = 0; m < 4; ++m) {
      afb[d][m] = *(const ll*)(ak + m * 512);
      bfb[d][m] = *(const ll*)(bk + m * 512);
    }
  }

  f32x4 acc[4][4] = {};
#pragma unroll 4
  for (int kb = 0; kb < KB; ++kb) {
    const int cur = kb & 3;
    if (kb + 3 < KB) {
      const int nxt = (kb + 3) & 3;
      const unsigned char* ak = aP + (size_t)(kb + 3) * 2048;
      const unsigned char* bk = bP + (size_t)(kb + 3) * 2048;
#pragma unroll
      for (int m = 0; m < 4; ++m) {
        afb[nxt][m] = *(const ll*)(ak + m * 512);
        bfb[nxt][m] = *(const ll*)(bk + m * 512);
      }
    }
#pragma unroll
    for (int mt = 0; mt < 4; ++mt)
#pragma unroll
      for (int nt = 0; nt < 4; ++nt)
        acc[mt][nt] = __builtin_amdgcn_mfma_f32_16x16x32_fp8_fp8(
            afb[cur][mt], bfb[cur][nt], acc[mt][nt], 0, 0, 0);
  }

  // ---- fused single-pass epilogue ----------------------------------------
  // element: row = mt*16 + (t>>4)*4 + r ; col = nt*16 + (t&15)
  int cl[4];
#pragma unroll
  for (int nt = 0; nt < 4; ++nt) cl[nt] = __shfl(myLC, nt * 16 + (t & 15), 64);
  const bool dg = (by == bx);

  float bps[4] = {}, bs1[4] = {}, bs2[4] = {};
  float bvm[4] = {-1e30f, -1e30f, -1e30f, -1e30f};

#pragma unroll
  for (int mt = 0; mt < 4; ++mt) {
#pragma unroll
    for (int r = 0; r < 4; ++r) {
      int rowL = mt * 16 + (t >> 4) * 4 + r;
      int lr = __shfl(myLR, rowL, 64);
      float ps = 0.f, s1 = 0.f, s2 = 0.f, vm = -1e30f;
#pragma unroll
      for (int nt = 0; nt < 4; ++nt) {
        float v = acc[mt][nt][r];
        int colL = nt * 16 + (t & 15);
        bool diag = dg && (rowL == colL);
        bool same = (lr == cl[nt]);
        float e10 = __expf(v * 10.f);
        float e20 = e10 * e10;
        s1 += diag ? 1.f : e10;
        ps += (same && !diag) ? v : 0.f;
        s2 += same ? 0.f : e20;
        vm = same ? vm : fmaxf(vm, v);
        if (!dg) {  // B-side accumulation (consumed only off-diagonal)
          bs1[nt] += e10;
          bps[nt] += same ? v : 0.f;
          bs2[nt] += same ? 0.f : e20;
          bvm[nt] = same ? bvm[nt] : fmaxf(bvm[nt], v);
        }
      }
#pragma unroll
      for (int o = 1; o < 16; o <<= 1) {
        ps += __shfl_xor(ps, o, 64);
        s1 += __shfl_xor(s1, o, 64);
        s2 += __shfl_xor(s2, o, 64);
        vm = fmaxf(vm, __shfl_xor(vm, o, 64));
      }
      if ((t & 15) == 0)
        part[(size_t)(rowBase + rowL) * NB + bx] =
            make_float4(ps, s1, s2, 20.f * vm);
    }
  }

  if (!dg) {
#pragma unroll
    for (int nt = 0; nt < 4; ++nt) {
      float ps = bps[nt], s1 = bs1[nt], s2 = bs2[nt], vm = bvm[nt];
#pragma unroll
      for (int o = 16; o < 64; o <<= 1) {
        ps += __shfl_xor(ps, o, 64);
        s1 += __shfl_xor(s1, o, 64);
        s2 += __shfl_xor(s2, o, 64);
        vm = fmaxf(vm, __shfl_xor(vm, o, 64));
      }
      if ((t >> 4) == 0)
        part[(size_t)(colBase + nt * 16 + (t & 15)) * NB + by] =
            make_float4(ps, s1, s2, 20.f * vm);
    }
  }
}

// --- 3. merge partials per row (64 colblocks -> full-wave reduce) ----------
__global__ void k_merge(const float4* __restrict__ part,
                        float* __restrict__ psumRow,
                        float* __restrict__ logS1, float* __restrict__ Srow,
                        int N, int NB) {
  int lane = threadIdx.x & 63;
  int w = threadIdx.x >> 6;
  int row = blockIdx.x * 4 + w;
  float ps = 0.f, s1 = 0.f, s2 = 0.f, m2 = -1e30f;
  if (lane < NB) {
    float4 p = part[(size_t)row * NB + lane];
    ps = p.x; s1 = p.y; s2 = p.z; m2 = p.w;
  }
#pragma unroll
  for (int o = 32; o > 0; o >>= 1) {
    ps += __shfl_down(ps, o, 64);
    s1 += __shfl_down(s1, o, 64);
    s2 += __shfl_down(s2, o, 64);
    m2 = fmaxf(m2, __shfl_down(m2, o, 64));
  }
  if (lane == 0) {
    psumRow[row] = ps;
    logS1[row] = logf(s1);
    Srow[row] = (m2 < -1e29f) ? 0.f : s2 * expf(-m2);
  }
}

// --- 4. finalize (atomic-free: LDS staging + per-class reductions) ---------
__global__ void k_final(const float* __restrict__ ce_row,
                        const float* __restrict__ psumRow,
                        const float* __restrict__ logS1,
                        const float* __restrict__ Srow,
                        const int* __restrict__ lab, float* __restrict__ out,
                        int N, int C) {
  extern __shared__ char sm[];
  float* sS = (float*)sm;            // N floats
  int* sL = (int*)(sm + (size_t)N * 4);  // N ints
  __shared__ float sbuf[8];
  __shared__ float cS[32];
  __shared__ int cCnt[32];
  for (int i = threadIdx.x; i < N; i += blockDim.x) {
    sS[i] = Srow[i];
    sL[i] = lab[i];
  }
  __syncthreads();
  for (int c = 0; c < C; ++c) {
    float s = 0.f, cnt = 0.f;
    for (int i = threadIdx.x; i < N; i += blockDim.x) {
      bool m = (sL[i] == c);
      s += m ? sS[i] : 0.f;
      cnt += m ? 1.f : 0.f;
    }
    s = blockReduceSum(s, sbuf);
    cnt = blockReduceSum(cnt, sbuf);
    if (threadIdx.x == 0) {
      cS[c] = s;
      cCnt[c] = (int)(cnt + 0.5f);
    }
  }
  __syncthreads();
  float sumCe = 0.f, sumP1 = 0.f;
  for (int i = threadIdx.x; i < N; i += blockDim.x) {
    sumCe += ce_row[i];
    int pc = cCnt[sL[i]] - 1;
    if (pc > 0) sumP1 += psumRow[i] * 10.f / (float)pc - logS1[i];
  }
  sumCe = blockReduceSum(sumCe, sbuf);
  sumP1 = blockReduceSum(sumP1, sbuf);
  if (threadIdx.x == 0) {
    float totS = 0.f;
    for (int c = 0; c < C; ++c) totS += cS[c];
    float l2sum = 0.f;
    for (int c = 0; c < C; ++c) {
      int cnt = cCnt[c];
      if (cnt >= 2) {
        float negs = (float)(N - cnt);
        float x = (totS - cS[c]) / negs;
        l2sum += (float)cnt * logf(x + 1e-12f);
      }
    }
    float ce = sumCe / (float)N;
    float ntx1 = -sumP1 / (float)N;
    float ntx2 = l2sum / (float)N;
    out[0] = 0.5f * ce + 0.5f * ntx1 + 0.25f * ntx2;
  }
}

extern "C" void kernel_launch(void* const* d_in, const int* in_sizes, int n_in,
                              void* d_out, int out_size, void* d_ws,
                              size_t ws_size, hipStream_t stream) {
  const float* X = (const float*)d_in[0];  // cls_feats [N,D]
  const float* P = (const float*)d_in[1];  // predicts  [N,C]
  const int* tgt = (const int*)d_in[2];    // targets   [N]
  float* out = (float*)d_out;

  int N = in_sizes[2];
  int D = in_sizes[0] / N;
  int C = in_sizes[1] / N;
  int NB = N / 64;

  char* ws = (char*)d_ws;
  uint2* Pk = (uint2*)ws;                        // N*D fp8 bytes, packed
  float4* part = (float4*)(ws + (size_t)N * D);  // N*NB float4
  float* ce_row = (float*)((char*)part + (size_t)N * NB * 16);
  float* psumRow = ce_row + N;
  float* logS1 = psumRow + N;
  float* Srow = logS1 + N;

  k_prep<<<N, 256, 0, stream>>>(X, P, tgt, Pk, ce_row, D, C);
  int nblk = NB * (NB + 1) / 2;
  k_gemm_fused<<<nblk, 64, 0, stream>>>((const unsigned char*)Pk, tgt, part,
                                        N, D, NB);
  k_merge<<<N / 4, 256, 0, stream>>>(part, psumRow, logS1, Srow, N, NB);
  k_final<<<1, 256, (size_t)N * 8, stream>>>(ce_row, psumRow, logS1, Srow,
                                             tgt, out, N, C);
}

// Round 14
// 125.405 us; speedup vs baseline: 1.6458x; 1.6458x over previous
//
#include <hip/hip_runtime.h>
#include <hip/hip_bf16.h>
#include <math.h>

// ---------------------------------------------------------------------------
// SupConLoss on MI355X.
// out = 0.5*CE(predicts,targets) + 0.5*nt_xent(Anorm, temp=0.1)
//       + 0.25*nt_xent2(Anorm, temp=0.05)
// Round 14: round-12 fp8 packed register-direct gemm + BLOCK-INTERNAL
// SPLIT-K (2 waves per 64x64 tile, each half of K), partial accumulators
// exchanged via 16 KB LDS so both waves hold the full tile; wave 0 does
// A-side stats, wave 1 B-side. Grid 2080 blocks x 2 waves = 16.25 waves/CU
// (round 12 was 8.1, latency-bound at Occ 10.5%); per-wave K-chain halves.
// K-loop kept byte-identical to round 12's pattern (round 13 proved hand
// register pipelines make the compiler's schedule WORSE: VGPR stayed 88,
// gemm 45.7->100.6).
// Exp sums unshifted (|exponent|<=20, fp32-safe); reference row-max shift
// applied exactly in merge: S_j = s2_raw * exp(-20*vmax_j).
// ---------------------------------------------------------------------------

typedef __attribute__((ext_vector_type(4))) float f32x4;
typedef long long ll;

__device__ __forceinline__ float blockReduceSum(float v, float* sbuf) {
#pragma unroll
  for (int o = 32; o > 0; o >>= 1) v += __shfl_down(v, o, 64);
  int lane = threadIdx.x & 63;
  int w = threadIdx.x >> 6;
  __syncthreads();
  if (lane == 0) sbuf[w] = v;
  __syncthreads();
  return sbuf[0] + sbuf[1] + sbuf[2] + sbuf[3];
}

// --- 1. fused normalize + fp8 fragment-pack + per-row CE -------------------
// Packed layout: 8B chunk index = ((strip*KB + kb)*4 + mt)*64 + lane
//   holds row = strip*64 + mt*16 + (lane&15),
//   k = kb*32 + (lane>>4)*8 .. +7   (one fp8 MFMA A/B fragment slice).
__global__ void k_prep(const float* __restrict__ X, const float* __restrict__ P,
                       const int* __restrict__ tgt, uint2* __restrict__ Pk,
                       float* __restrict__ ce_row, int D, int C) {
  __shared__ float sbuf[8];
  int row = blockIdx.x;
  const float* x = X + (size_t)row * D;
  float ss = 0.f;
  for (int j = threadIdx.x; j < D; j += blockDim.x) {
    float v = x[j];
    ss += v * v;
  }
  ss = blockReduceSum(ss, sbuf);
  float inv = 1.0f / fmaxf(sqrtf(ss), 1e-12f);

  const int KB = D / 32;           // 24
  const int strip = row >> 6;
  const int mt = (row >> 4) & 3;
  const int l4 = row & 15;
  const int nchunk = D / 8;        // 96
  for (int c = threadIdx.x; c < nchunk; c += blockDim.x) {
    int kb = c >> 2;
    int lsub = c & 3;
    int k0 = kb * 32 + lsub * 8;
    float v[8];
#pragma unroll
    for (int j = 0; j < 8; ++j) v[j] = x[k0 + j] * inv;
    unsigned int r0 = 0, r1 = 0;
    r0 = __builtin_amdgcn_cvt_pk_fp8_f32(v[0], v[1], r0, 0);
    r0 = __builtin_amdgcn_cvt_pk_fp8_f32(v[2], v[3], r0, 1);
    r1 = __builtin_amdgcn_cvt_pk_fp8_f32(v[4], v[5], r1, 0);
    r1 = __builtin_amdgcn_cvt_pk_fp8_f32(v[6], v[7], r1, 1);
    int lane = l4 + 16 * lsub;
    size_t chunk = ((size_t)(strip * KB + kb) * 4 + mt) * 64 + lane;
    Pk[chunk] = make_uint2(r0, r1);
  }
  if (threadIdx.x == 0) {
    const float* p = P + (size_t)row * C;
    float m = -INFINITY;
    for (int c = 0; c < C; ++c) m = fmaxf(m, p[c]);
    float s = 0.f;
    for (int c = 0; c < C; ++c) s += expf(p[c] - m);
    int t = tgt[row];
    ce_row[row] = -(p[t] - m - logf(s));
  }
}

// --- 2. 2-wave split-K 64x64 fused symmetric GEMM + stats, fp8 packed ------
// part layout: float4 part[N][NB]; (psum, s1_raw, s2_raw, m2=20*vmax_neg).
__global__ __launch_bounds__(128) void k_gemm_fused(
    const unsigned char* __restrict__ Pk, const int* __restrict__ lab,
    float4* __restrict__ part, int N, int K, int NB) {
  __shared__ f32x4 xch[4][4][64];  // 16 KB accumulator exchange

  // triangular decode: bid -> (by, bx), by >= bx
  int bid = blockIdx.x;
  int by = (int)((sqrtf(8.f * (float)bid + 1.f) - 1.f) * 0.5f);
  while ((by + 1) * (by + 2) / 2 <= bid) ++by;
  while (by * (by + 1) / 2 > bid) --by;
  int bx = bid - by * (by + 1) / 2;

  const int t = threadIdx.x & 63;
  const int wv = threadIdx.x >> 6;  // 0 or 1
  const int rowBase = by * 64;
  const int colBase = bx * 64;
  const int KB = K / 32;        // 24
  const int KBh = KB >> 1;      // 12 per wave

  const int myLR = lab[rowBase + t];
  const int myLC = lab[colBase + t];

  // byte offsets: chunk = ((strip*KB+kb)*4+mt)*64 + lane, 8 bytes each;
  // this wave's K-half starts at kb = wv*KBh.
  const unsigned char* aP =
      Pk + ((size_t)by * KB * 4 * 64 + t) * 8 + (size_t)wv * KBh * 2048;
  const unsigned char* bP =
      Pk + ((size_t)bx * KB * 4 * 64 + t) * 8 + (size_t)wv * KBh * 2048;

  f32x4 acc[4][4] = {};
#pragma unroll 4
  for (int kb = 0; kb < KBh; ++kb) {
    ll af[4], bf[4];
    const unsigned char* ak = aP + (size_t)kb * 2048;  // 4 mt * 64 lanes * 8B
    const unsigned char* bk = bP + (size_t)kb * 2048;
#pragma unroll
    for (int mt = 0; mt < 4; ++mt) af[mt] = *(const ll*)(ak + mt * 512);
#pragma unroll
    for (int nt = 0; nt < 4; ++nt) bf[nt] = *(const ll*)(bk + nt * 512);
#pragma unroll
    for (int mt = 0; mt < 4; ++mt)
#pragma unroll
      for (int nt = 0; nt < 4; ++nt)
        acc[mt][nt] = __builtin_amdgcn_mfma_f32_16x16x32_fp8_fp8(
            af[mt], bf[nt], acc[mt][nt], 0, 0, 0);
  }

  // ---- accumulator exchange: both waves end with the FULL tile -----------
  if (wv == 0) {
#pragma unroll
    for (int mt = 0; mt < 4; ++mt)
#pragma unroll
      for (int nt = 0; nt < 4; ++nt) xch[mt][nt][t] = acc[mt][nt];
  }
  __syncthreads();
  if (wv == 1) {
#pragma unroll
    for (int mt = 0; mt < 4; ++mt)
#pragma unroll
      for (int nt = 0; nt < 4; ++nt) {
        acc[mt][nt] += xch[mt][nt][t];
        xch[mt][nt][t] = acc[mt][nt];
      }
  }
  __syncthreads();
  if (wv == 0) {
#pragma unroll
    for (int mt = 0; mt < 4; ++mt)
#pragma unroll
      for (int nt = 0; nt < 4; ++nt) acc[mt][nt] = xch[mt][nt][t];
  }

  // ---- epilogue: wave 0 = A-side rows, wave 1 = B-side cols ---------------
  // element: row = mt*16 + (t>>4)*4 + r ; col = nt*16 + (t&15)
  int cl[4];
#pragma unroll
  for (int nt = 0; nt < 4; ++nt) cl[nt] = __shfl(myLC, nt * 16 + (t & 15), 64);
  const bool dg = (by == bx);

  if (wv == 0) {
#pragma unroll
    for (int mt = 0; mt < 4; ++mt) {
#pragma unroll
      for (int r = 0; r < 4; ++r) {
        int rowL = mt * 16 + (t >> 4) * 4 + r;
        int lr = __shfl(myLR, rowL, 64);
        float ps = 0.f, s1 = 0.f, s2 = 0.f, vm = -1e30f;
#pragma unroll
        for (int nt = 0; nt < 4; ++nt) {
          float v = acc[mt][nt][r];
          int colL = nt * 16 + (t & 15);
          bool diag = dg && (rowL == colL);
          bool same = (lr == cl[nt]);
          float e10 = __expf(v * 10.f);
          float e20 = e10 * e10;
          s1 += diag ? 1.f : e10;
          ps += (same && !diag) ? v : 0.f;
          s2 += same ? 0.f : e20;
          vm = same ? vm : fmaxf(vm, v);
        }
#pragma unroll
        for (int o = 1; o < 16; o <<= 1) {
          ps += __shfl_xor(ps, o, 64);
          s1 += __shfl_xor(s1, o, 64);
          s2 += __shfl_xor(s2, o, 64);
          vm = fmaxf(vm, __shfl_xor(vm, o, 64));
        }
        if ((t & 15) == 0)
          part[(size_t)(rowBase + rowL) * NB + bx] =
              make_float4(ps, s1, s2, 20.f * vm);
      }
    }
  } else if (!dg) {
#pragma unroll
    for (int nt = 0; nt < 4; ++nt) {
      int lc = cl[nt];
      float ps = 0.f, s1 = 0.f, s2 = 0.f, vm = -1e30f;
#pragma unroll
      for (int mt = 0; mt < 4; ++mt)
#pragma unroll
        for (int r = 0; r < 4; ++r) {
          float v = acc[mt][nt][r];
          int rowL = mt * 16 + (t >> 4) * 4 + r;
          int lr = __shfl(myLR, rowL, 64);
          bool same = (lr == lc);
          float e10 = __expf(v * 10.f);
          s1 += e10;
          ps += same ? v : 0.f;
          s2 += same ? 0.f : e10 * e10;
          vm = same ? vm : fmaxf(vm, v);
        }
#pragma unroll
      for (int o = 16; o < 64; o <<= 1) {
        ps += __shfl_xor(ps, o, 64);
        s1 += __shfl_xor(s1, o, 64);
        s2 += __shfl_xor(s2, o, 64);
        vm = fmaxf(vm, __shfl_xor(vm, o, 64));
      }
      if ((t >> 4) == 0)
        part[(size_t)(colBase + nt * 16 + (t & 15)) * NB + by] =
            make_float4(ps, s1, s2, 20.f * vm);
    }
  }
}

// --- 3. merge partials per row (64 colblocks -> full-wave reduce) ----------
__global__ void k_merge(const float4* __restrict__ part,
                        float* __restrict__ psumRow,
                        float* __restrict__ logS1, float* __restrict__ Srow,
                        int N, int NB) {
  int lane = threadIdx.x & 63;
  int w = threadIdx.x >> 6;
  int row = blockIdx.x * 4 + w;
  float ps = 0.f, s1 = 0.f, s2 = 0.f, m2 = -1e30f;
  if (lane < NB) {
    float4 p = part[(size_t)row * NB + lane];
    ps = p.x; s1 = p.y; s2 = p.z; m2 = p.w;
  }
#pragma unroll
  for (int o = 32; o > 0; o >>= 1) {
    ps += __shfl_down(ps, o, 64);
    s1 += __shfl_down(s1, o, 64);
    s2 += __shfl_down(s2, o, 64);
    m2 = fmaxf(m2, __shfl_down(m2, o, 64));
  }
  if (lane == 0) {
    psumRow[row] = ps;
    logS1[row] = logf(s1);
    Srow[row] = (m2 < -1e29f) ? 0.f : s2 * expf(-m2);
  }
}

// --- 4. finalize ----------------------------------------------------------
__global__ void k_final(const float* __restrict__ ce_row,
                        const float* __restrict__ psumRow,
                        const float* __restrict__ logS1,
                        const float* __restrict__ Srow,
                        const int* __restrict__ lab, float* __restrict__ out,
                        int N, int C) {
  __shared__ float classS[32];
  __shared__ int classCnt[32];
  __shared__ float sbuf[8];
  if (threadIdx.x < 32) {
    classS[threadIdx.x] = 0.f;
    classCnt[threadIdx.x] = 0;
  }
  __syncthreads();
  float sumCe = 0.f;
  for (int i = threadIdx.x; i < N; i += blockDim.x) {
    sumCe += ce_row[i];
    int l = lab[i];
    atomicAdd(&classCnt[l], 1);
    atomicAdd(&classS[l], Srow[i]);
  }
  __syncthreads();
  float sumP1 = 0.f;
  for (int i = threadIdx.x; i < N; i += blockDim.x) {
    int l = lab[i];
    int pc = classCnt[l] - 1;
    if (pc > 0) sumP1 += psumRow[i] * 10.f / (float)pc - logS1[i];
  }
  sumCe = blockReduceSum(sumCe, sbuf);
  sumP1 = blockReduceSum(sumP1, sbuf);
  if (threadIdx.x == 0) {
    float totS = 0.f;
    for (int c = 0; c < C; ++c) totS += classS[c];
    float l2sum = 0.f;
    for (int c = 0; c < C; ++c) {
      int cnt = classCnt[c];
      if (cnt >= 2) {
        float negs = (float)(N - cnt);
        float x = (totS - classS[c]) / negs;
        l2sum += (float)cnt * logf(x + 1e-12f);
      }
    }
    float ce = sumCe / (float)N;
    float ntx1 = -sumP1 / (float)N;
    float ntx2 = l2sum / (float)N;
    out[0] = 0.5f * ce + 0.5f * ntx1 + 0.25f * ntx2;
  }
}

extern "C" void kernel_launch(void* const* d_in, const int* in_sizes, int n_in,
                              void* d_out, int out_size, void* d_ws,
                              size_t ws_size, hipStream_t stream) {
  const float* X = (const float*)d_in[0];  // cls_feats [N,D]
  const float* P = (const float*)d_in[1];  // predicts  [N,C]
  const int* tgt = (const int*)d_in[2];    // targets   [N]
  float* out = (float*)d_out;

  int N = in_sizes[2];
  int D = in_sizes[0] / N;
  int C = in_sizes[1] / N;
  int NB = N / 64;

  char* ws = (char*)d_ws;
  uint2* Pk = (uint2*)ws;                        // N*D fp8 bytes, packed
  float4* part = (float4*)(ws + (size_t)N * D);  // N*NB float4
  float* ce_row = (float*)((char*)part + (size_t)N * NB * 16);
  float* psumRow = ce_row + N;
  float* logS1 = psumRow + N;
  float* Srow = logS1 + N;

  k_prep<<<N, 256, 0, stream>>>(X, P, tgt, Pk, ce_row, D, C);
  int nblk = NB * (NB + 1) / 2;
  k_gemm_fused<<<nblk, 128, 0, stream>>>((const unsigned char*)Pk, tgt, part,
                                         N, D, NB);
  k_merge<<<N / 4, 256, 0, stream>>>(part, psumRow, logS1, Srow, N, NB);
  k_final<<<1, 256, 0, stream>>>(ce_row, psumRow, logS1, Srow, tgt, out, N, C);
}